// Round 5
// baseline (187.120 us; speedup 1.0000x reference)
//
#include <hip/hip_runtime.h>

#define B_G   100
#define N_PER 1000
#define E_PER 12000
#define NTOT  (B_G * N_PER)
#define ETOT  (B_G * E_PER)
#define KSEL  800
#define EPT   12

typedef __attribute__((ext_vector_type(8))) short short8;
typedef __attribute__((ext_vector_type(4))) float float4_;

__device__ __forceinline__ unsigned short f2bf(float f) {
    unsigned u = __float_as_uint(f);
    u += 0x7fffu + ((u >> 16) & 1u);          // RNE
    return (unsigned short)(u >> 16);
}
__device__ __forceinline__ float upk(unsigned q) {          // bf16 ew in hi16
    return __uint_as_float(q & 0xFFFF0000u);
}
// fp8 e4m3 (z>=0): raw decode = true_value * 2^-120 (exact, incl subnormals)
__device__ __forceinline__ float dec_raw(unsigned byte7f) { // pass (b&0x7f)
    return __uint_as_float(byte7f << 20);
}
__device__ __forceinline__ unsigned enc_fp8(float z) {      // z >= 0, z < 448
    unsigned u = __float_as_uint(z * 0x1p-120f);
    u += 0x7FFFFu + ((u >> 20) & 1u);                       // RNE at bit 20
    return u >> 20;
}

// conv2 aggregation for one constant TI; results into named short8 AF0/AF1.
// r3: named vars + literal TI keep fragments off the stack.
// r5: 1-deep software pipeline — prefetch edge k+1's csr entry + zs row while
// the 64-fma decode of edge k executes; runtime trip count blocks the compiler
// from doing this itself. Accumulation order unchanged (bit-exact).
#define CONV2_TI(TI, AF0, AF1) do {                                            \
    const int t_ = wid + (TI) * 16;                                            \
    const int li_ = t_ * 16 + nloc;                                            \
    const bool valid_ = li_ < N_PER;                                           \
    float acc_[16];                                                            \
    int s_ = 0, cn_ = 0;                                                       \
    if (valid_) {                                                              \
        uint4 rv_ = *(const uint4*)(zs + li_ * 64 + ((kgrp ^ ((li_ >> 1) & 3)) << 4)); \
        _Pragma("unroll")                                                      \
        for (int j = 0; j < 4; j++) {                                          \
            acc_[j]      = dec_raw((rv_.x >> (8 * j)) & 0x7Fu);                \
            acc_[4 + j]  = dec_raw((rv_.y >> (8 * j)) & 0x7Fu);                \
            acc_[8 + j]  = dec_raw((rv_.z >> (8 * j)) & 0x7Fu);                \
            acc_[12 + j] = dec_raw((rv_.w >> (8 * j)) & 0x7Fu);                \
        }                                                                      \
        s_ = li_ ? ends[li_ - 1] : 0;                                          \
        cn_ = ends[li_] - s_;                                                  \
    } else {                                                                   \
        _Pragma("unroll")                                                      \
        for (int j = 0; j < 16; j++) acc_[j] = 0.f;                            \
    }                                                                          \
    int mx_ = cn_;                                                             \
    _Pragma("unroll")                                                          \
    for (int m = 1; m < 16; m <<= 1) mx_ = max(mx_, __shfl_xor(mx_, m));       \
    unsigned qc_ = (0 < cn_) ? csr[s_] : 0u;                                   \
    int sc_ = (int)(qc_ & 0xFFFFu);                                            \
    uint4 rc_ = *(const uint4*)(zs + sc_ * 64 + ((kgrp ^ ((sc_ >> 1) & 3)) << 4)); \
    for (int k = 0; k < mx_; k++) {                                            \
        unsigned qn_ = (k + 1 < cn_) ? csr[s_ + k + 1] : 0u;                   \
        int sn_ = (int)(qn_ & 0xFFFFu);                                        \
        uint4 rn_ = *(const uint4*)(zs + sn_ * 64 + ((kgrp ^ ((sn_ >> 1) & 3)) << 4)); \
        if (k < cn_) {                                                         \
            float wv_ = upk(qc_);                                              \
            _Pragma("unroll")                                                  \
            for (int j = 0; j < 4; j++) {                                      \
                acc_[j]      += wv_ * dec_raw((rc_.x >> (8 * j)) & 0x7Fu);     \
                acc_[4 + j]  += wv_ * dec_raw((rc_.y >> (8 * j)) & 0x7Fu);     \
                acc_[8 + j]  += wv_ * dec_raw((rc_.z >> (8 * j)) & 0x7Fu);     \
                acc_[12 + j] += wv_ * dec_raw((rc_.w >> (8 * j)) & 0x7Fu);     \
            }                                                                  \
        }                                                                      \
        qc_ = qn_; rc_ = rn_;                                                  \
    }                                                                          \
    float scale_ = (valid_ ? dl[li_] : 0.f) * 0x1p120f;                        \
    _Pragma("unroll")                                                          \
    for (int j = 0; j < 8; j++) {                                              \
        AF0[j] = (short)f2bf(scale_ * acc_[j]);                                \
        AF1[j] = (short)f2bf(scale_ * acc_[8 + j]);                            \
    }                                                                          \
} while (0)

// W2 MFMA + epilogue for one constant TI (guard replaces the old `continue`).
#define W2_TI(TI, AF0, AF1) do {                                               \
    const int t_ = wid + (TI) * 16;                                            \
    if (t_ < 63) {                                                             \
        float4_ accv_[4];                                                      \
        _Pragma("unroll")                                                      \
        for (int c = 0; c < 4; ++c) accv_[c] = (float4_){0.f, 0.f, 0.f, 0.f};  \
        _Pragma("unroll")                                                      \
        for (int c = 0; c < 4; ++c) {                                          \
            accv_[c] = __builtin_amdgcn_mfma_f32_16x16x32_bf16(AF0, Bf[0][c], accv_[c], 0, 0, 0); \
            accv_[c] = __builtin_amdgcn_mfma_f32_16x16x32_bf16(AF1, Bf[1][c], accv_[c], 0, 0, 0); \
        }                                                                      \
        _Pragma("unroll")                                                      \
        for (int r2 = 0; r2 < 4; ++r2) {                                       \
            int li2_ = t_ * 16 + kgrp * 4 + r2;                                \
            bool valid2_ = li2_ < N_PER;                                       \
            float sp_ = 0.f;                                                   \
            _Pragma("unroll")                                                  \
            for (int c = 0; c < 4; ++c) {                                      \
                float hv_ = fmaxf(accv_[c][r2] + b2c[c], 0.f);                 \
                sp_ += hv_ * pwc[c];                                           \
                if (valid2_) zs[li2_ * 64 + c * 16 + nloc] = (unsigned char)enc_fp8(hv_); \
            }                                                                  \
            _Pragma("unroll")                                                  \
            for (int m = 1; m < 16; m <<= 1) sp_ += __shfl_xor(sp_, m);        \
            if (valid2_ && nloc == 0) {                                        \
                float scv_ = tanhf(sp_ * invn);                                \
                unsigned bits_ = __float_as_uint(scv_);                        \
                unsigned u_ = (bits_ & 0x80000000u) ? ~bits_ : (bits_ | 0x80000000u); \
                keys[li2_] = ((unsigned long long)u_ << 32) | (unsigned)(1023 - li2_); \
            }                                                                  \
        }                                                                      \
    }                                                                          \
} while (0)

// ===== whole network, one block per graph, EVERYTHING (incl CSR) in LDS =====
// LDS map (136832 B):
//  [0,64000)    zs: fp8 z rows (64 B, chunk-swizzled); xl f[3000] early; h2 linear late
//  [64000)      csr u32[12000]  (bf16 ew <<16 | src)
//  [112000)     ends int[1024]  (inclusive rowptr)
//  [116096)     dl f[1024]      (aliases posc during fill)
//  [120192)     wpart i[16] / x1b f[64]
//  [120448)     uA 16384: aggv f[3000] / keys u64[1024]; sred@12288;
//               red@8192; a1@12288 a2@12544 zb@12672
__global__ __launch_bounds__(1024)
__attribute__((amdgpu_waves_per_eu(4, 4))) void k_all(
    const int* __restrict__ ei, const float* __restrict__ ew,
    const float* __restrict__ x,
    const float* __restrict__ w1, const float* __restrict__ b1,
    const float* __restrict__ w2, const float* __restrict__ b2,
    const float* __restrict__ pw,
    const float* __restrict__ l1w, const float* __restrict__ l1b,
    const float* __restrict__ l2w, const float* __restrict__ l2b,
    const float* __restrict__ l3w, const float* __restrict__ l3b,
    float* __restrict__ out) {
    __shared__ __align__(16) unsigned char smem[136832];
    unsigned char* zs = smem;
    float* xl = (float*)smem;
    unsigned* csr = (unsigned*)(smem + 64000);
    int*   ends = (int*)(smem + 112000);
    float* dl   = (float*)(smem + 116096);
    int*   posc = (int*)(smem + 116096);         // alias, dead before dl
    int*   wpart = (int*)(smem + 120192);
    float* x1b   = (float*)(smem + 120192);
    unsigned char* uA = smem + 120448;
    float* aggv = (float*)uA;

    int b = blockIdx.x, tid = threadIdx.x;
    int wid = tid >> 6, lane = tid & 63;
    int gbase = b * N_PER, ebase = b * E_PER;

    // ---- phase 0: edges into regs (read once), xl load, init ----
    int esrc[EPT], edst[EPT]; float eww[EPT];
    int ne = (tid < (E_PER - (EPT - 1) * 1024)) ? EPT : EPT - 1;
#pragma unroll
    for (int i = 0; i < EPT; i++) {
        if (i < ne) {
            int e = tid + i * 1024;
            esrc[i] = ei[ebase + e] - gbase;
            edst[i] = ei[ETOT + ebase + e] - gbase;
            eww[i]  = ew[ebase + e];
        }
    }
    ends[tid] = 0;
    for (int i = tid; i < N_PER * 3; i += 1024) xl[i] = x[(size_t)gbase * 3 + i];
    __syncthreads();
    // ---- count ----
#pragma unroll
    for (int i = 0; i < EPT; i++)
        if (i < ne) atomicAdd(&ends[edst[i]], 1);
    __syncthreads();
    // ---- shuffle inclusive scan ----
    int v = ends[tid];
    int sc = v;
#pragma unroll
    for (int m = 1; m < 64; m <<= 1) {
        int t = __shfl_up(sc, m);
        if (lane >= m) sc += t;
    }
    if (lane == 63) wpart[wid] = sc;
    __syncthreads();
    if (tid < 16) {
        int s2 = wpart[tid];
#pragma unroll
        for (int m = 1; m < 16; m <<= 1) {
            int t = __shfl_up(s2, m);
            if (tid >= m) s2 += t;
        }
        wpart[tid] = s2;
    }
    __syncthreads();
    int incl = sc + (wid > 0 ? wpart[wid - 1] : 0);
    ends[tid] = incl;
    posc[tid] = incl - v;
    __syncthreads();
    // ---- CSR fill into LDS ----
#pragma unroll
    for (int i = 0; i < EPT; i++)
        if (i < ne) {
            int p = atomicAdd(&posc[edst[i]], 1);
            csr[p] = ((unsigned)f2bf(eww[i]) << 16) | (unsigned)esrc[i];
        }
    __syncthreads();
    // ---- wsum (LDS csr) -> dl; y = dl*x in place ----
    float dmy = 0.f;
    int s0i = 0, e0i = 0;
    if (tid < N_PER) {
        s0i = tid ? ends[tid - 1] : 0;
        e0i = ends[tid];
        float s0 = 0.f, s1 = 0.f;
        int k = s0i;
        for (; k + 2 <= e0i; k += 2) { s0 += upk(csr[k]); s1 += upk(csr[k + 1]); }
        if (k < e0i) s0 += upk(csr[k]);
        dmy = rsqrtf(s0 + s1 + 1.0f);
        dl[tid] = dmy;                            // posc dead (fill barrier above)
        xl[tid * 3 + 0] *= dmy;
        xl[tid * 3 + 1] *= dmy;
        xl[tid * 3 + 2] *= dmy;
    }
    __syncthreads();
    // ---- conv1 gather (1-deep pipelined): agg = dl*(y_self + sum ew*y_src) --
    if (tid < N_PER) {
        float a0 = xl[tid * 3 + 0], a1 = xl[tid * 3 + 1], a2 = xl[tid * 3 + 2];
        unsigned qc = (s0i < e0i) ? csr[s0i] : 0u;
        int ic = (int)(qc & 0xFFFFu) * 3;
        float xc0 = xl[ic], xc1 = xl[ic + 1], xc2 = xl[ic + 2];
        for (int k = s0i; k < e0i; k++) {
            unsigned qn = (k + 1 < e0i) ? csr[k + 1] : 0u;
            int in_ = (int)(qn & 0xFFFFu) * 3;
            float xn0 = xl[in_], xn1 = xl[in_ + 1], xn2 = xl[in_ + 2];
            float wv = upk(qc);
            a0 += wv * xc0; a1 += wv * xc1; a2 += wv * xc2;
            qc = qn; xc0 = xn0; xc1 = xn1; xc2 = xn2;
        }
        aggv[tid * 3 + 0] = dmy * a0;
        aggv[tid * 3 + 1] = dmy * a1;
        aggv[tid * 3 + 2] = dmy * a2;
    }
    __syncthreads();
    // ---- W1 (pipelined): h1 = relu(agg@W1+b1); z -> fp8 swizzled; x1 partials
    {
        float w0 = w1[lane], w1v = w1[64 + lane], w2v = w1[128 + lane], bf = b1[lane];
        float* sred = (float*)(uA + 12288);
        float px = 0.f;
        int chunk = (lane & 31) >> 3;
        int word  = ((lane >= 32) ? 2 : 0) + ((lane & 7) >> 2);
        float pa0 = aggv[wid * 3], pa1 = aggv[wid * 3 + 1], pa2 = aggv[wid * 3 + 2];
        float pdl = dl[wid];
        for (int node = wid; node < N_PER; node += 16) {
            int nn = node + 16;
            float na0 = 0.f, na1 = 0.f, na2 = 0.f, ndl = 0.f;
            if (nn < N_PER) {
                na0 = aggv[nn * 3]; na1 = aggv[nn * 3 + 1]; na2 = aggv[nn * 3 + 2];
                ndl = dl[nn];
            }
            float hv = fmaxf(pa0 * w0 + pa1 * w1v + pa2 * w2v + bf, 0.f);
            px += hv;
            unsigned byte = enc_fp8(pdl * hv);
            unsigned t1 = __shfl_xor(byte, 1);
            unsigned v16 = (lane & 1) ? (t1 | (byte << 8)) : (byte | (t1 << 8));
            unsigned t2 = __shfl_xor(v16, 2);
            unsigned v32 = (lane & 2) ? (t2 | (v16 << 16)) : (v16 | (t2 << 16));
            if ((lane & 3) == 0) {
                int cs = chunk ^ ((node >> 1) & 3);
                *(unsigned*)(zs + node * 64 + cs * 16 + word * 4) = v32;
            }
            pa0 = na0; pa1 = na1; pa2 = na2; pdl = ndl;
        }
        sred[wid * 64 + lane] = px;
        __syncthreads();
        if (tid < 64) {
            float t = 0.f;
            for (int r = 0; r < 16; r++) t += sred[r * 64 + tid];
            x1b[tid] = t * (1.0f / N_PER);
        }
    }
    // (zs complete at sred barrier; conv2 may proceed)
    // ---- conv2 agg in A-frag layout: g = dl*(z_self + sum ew*z_src) --------
    int kgrp = lane >> 4, nloc = lane & 15;
    short8 Af0a, Af0b, Af1a, Af1b, Af2a, Af2b, Af3a, Af3b;
    CONV2_TI(0, Af0a, Af0b);
    CONV2_TI(1, Af1a, Af1b);
    CONV2_TI(2, Af2a, Af2b);
    CONV2_TI(3, Af3a, Af3b);
    __syncthreads();   // all z reads done; zs may be overwritten with h2
    // ---- W2 via MFMA + epilogue (h2 fp8 linear -> zs, scores -> keys) ------
    unsigned long long* keys = (unsigned long long*)uA;
    {
        short8 Bf[2][4];
#pragma unroll
        for (int kh = 0; kh < 2; ++kh)
#pragma unroll
            for (int c = 0; c < 4; ++c) {
                short8 t;
#pragma unroll
                for (int j = 0; j < 8; ++j)
                    t[j] = (short)f2bf(w2[(kh * 32 + kgrp * 8 + j) * 64 + c * 16 + nloc]);
                Bf[kh][c] = t;
            }
        float b2c[4], pwc[4];
#pragma unroll
        for (int c = 0; c < 4; ++c) {
            b2c[c] = b2[c * 16 + nloc];
            pwc[c] = pw[c * 16 + nloc];
        }
        float invn;
        {
            float p = pw[lane], pn = p * p;
#pragma unroll
            for (int m = 32; m; m >>= 1) pn += __shfl_xor(pn, m);
            invn = rsqrtf(pn);
        }
        if (tid >= N_PER) keys[tid] = 0ull;      // pad entries sort last
        W2_TI(0, Af0a, Af0b);
        W2_TI(1, Af1a, Af1b);
        W2_TI(2, Af2a, Af2b);
        W2_TI(3, Af3a, Af3b);
    }
    __syncthreads();
    // ---- hybrid bitonic sort: j<64 via shfl, j>=64 via LDS ----
    {
        unsigned long long key = keys[tid];
        for (int k = 2; k <= 1024; k <<= 1) {
            for (int j = k >> 1; j > 0; j >>= 1) {
                bool desc = (tid & k) == 0;
                unsigned long long p;
                if (j >= 64) {
                    keys[tid] = key;
                    __syncthreads();
                    p = keys[tid ^ j];
                    __syncthreads();
                } else {
                    p = __shfl_xor(key, j);
                }
                bool low = (tid & j) == 0;
                bool sw = low ? (desc ? (key < p) : (key > p))
                              : (desc ? (p < key) : (p > key));
                if (sw) key = p;
            }
        }
        keys[tid] = key;
    }
    __syncthreads();
    // ---- weighted mean over top-K (h2 fp8 from LDS) + MLP ----
    float* red   = (float*)(uA + 8192);
    float* a1buf = (float*)(uA + 12288);
    float* a2buf = (float*)(uA + 12544);
    float* zbuf  = (float*)(uA + 12672);
    {
        int f = tid & 63, w16 = tid >> 6;
        float acc2 = 0.f;
        for (int r = w16; r < KSEL; r += 16) {
            unsigned long long key = keys[r];
            int idx = 1023 - (int)(key & 0xFFFFFFFFu);
            unsigned u = (unsigned)(key >> 32);
            unsigned bits = (u & 0x80000000u) ? (u & 0x7FFFFFFFu) : ~u;
            float valS = __uint_as_float(bits) * 0x1p120f;
            acc2 += valS * dec_raw((unsigned)zs[idx * 64 + f] & 0x7Fu);
        }
        red[tid] = acc2;
    }
    __syncthreads();
    if (tid < 64) {
        float s2 = 0.f;
        for (int ww = 0; ww < 16; ww++) s2 += red[ww * 64 + tid];
        zbuf[tid] = x1b[tid] + s2 * (1.0f / KSEL);
    }
    __syncthreads();
    if (tid < 64) {
        float a = l1b[tid];
        for (int k = 0; k < 64; k++) a += zbuf[k] * l1w[k * 64 + tid];
        a1buf[tid] = fmaxf(a, 0.f);
    }
    __syncthreads();
    if (tid < 32) {
        float a = l2b[tid];
        for (int k = 0; k < 64; k++) a += a1buf[k] * l2w[k * 32 + tid];
        a2buf[tid] = fmaxf(a, 0.f);
    }
    __syncthreads();
    if (tid == 0) {
        float t = l3b[0];
        for (int k = 0; k < 32; k++) t += a2buf[k] * l3w[k];
        out[b] = 1.0f / (1.0f + expf(-t));
    }
}

extern "C" void kernel_launch(void* const* d_in, const int* in_sizes, int n_in,
                              void* d_out, int out_size, void* d_ws, size_t ws_size,
                              hipStream_t stream) {
    const float* x   = (const float*)d_in[0];
    const int*   ei  = (const int*)d_in[1];
    const float* ew  = (const float*)d_in[2];
    const float* c1w = (const float*)d_in[4];
    const float* c1b = (const float*)d_in[5];
    const float* c2w = (const float*)d_in[6];
    const float* c2b = (const float*)d_in[7];
    const float* pw  = (const float*)d_in[8];
    const float* l1w = (const float*)d_in[9];
    const float* l1b = (const float*)d_in[10];
    const float* l2w = (const float*)d_in[11];
    const float* l2b = (const float*)d_in[12];
    const float* l3w = (const float*)d_in[13];
    const float* l3b = (const float*)d_in[14];
    float* out = (float*)d_out;
    (void)d_ws; (void)ws_size; (void)in_sizes; (void)n_in; (void)out_size;

    k_all<<<B_G, 1024, 0, stream>>>(ei, ew, x, c1w, c1b, c2w, c2b, pw,
                                    l1w, l1b, l2w, l2b, l3w, l3b, out);
}

// Round 7
// 171.321 us; speedup vs baseline: 1.0922x; 1.0922x over previous
//
#include <hip/hip_runtime.h>

#define B_G   100
#define N_PER 1000
#define E_PER 12000
#define NTOT  (B_G * N_PER)
#define ETOT  (B_G * E_PER)
#define KSEL  800
#define EPT   12

typedef __attribute__((ext_vector_type(8))) short short8;
typedef __attribute__((ext_vector_type(4))) float float4_;

__device__ __forceinline__ unsigned short f2bf(float f) {
    unsigned u = __float_as_uint(f);
    u += 0x7fffu + ((u >> 16) & 1u);          // RNE
    return (unsigned short)(u >> 16);
}
__device__ __forceinline__ float upk(unsigned q) {          // bf16 ew in hi16
    return __uint_as_float(q & 0xFFFF0000u);
}
// fp8 e4m3 (z>=0): raw decode = true_value * 2^-120 (exact, incl subnormals)
__device__ __forceinline__ float dec_raw(unsigned byte7f) { // pass (b&0x7f)
    return __uint_as_float(byte7f << 20);
}
__device__ __forceinline__ unsigned enc_fp8(float z) {      // z >= 0, z < 448
    unsigned u = __float_as_uint(z * 0x1p-120f);
    u += 0x7FFFFu + ((u >> 20) & 1u);                       // RNE at bit 20
    return u >> 20;
}

// conv2 aggregation for one TI (runtime TI ok: used arithmetically only);
// results into named short8 AF0/AF1 (r3: named vars keep fragments off stack).
#define CONV2_TI(TI, AF0, AF1) do {                                            \
    const int t_ = wid + (TI) * 16;                                            \
    const int li_ = t_ * 16 + nloc;                                            \
    const bool valid_ = li_ < N_PER;                                           \
    float acc_[16];                                                            \
    int s_ = 0, cn_ = 0;                                                       \
    if (valid_) {                                                              \
        uint4 rv_ = *(const uint4*)(zs + li_ * 64 + ((kgrp ^ ((li_ >> 1) & 3)) << 4)); \
        _Pragma("unroll")                                                      \
        for (int j = 0; j < 4; j++) {                                          \
            acc_[j]      = dec_raw((rv_.x >> (8 * j)) & 0x7Fu);                \
            acc_[4 + j]  = dec_raw((rv_.y >> (8 * j)) & 0x7Fu);                \
            acc_[8 + j]  = dec_raw((rv_.z >> (8 * j)) & 0x7Fu);                \
            acc_[12 + j] = dec_raw((rv_.w >> (8 * j)) & 0x7Fu);                \
        }                                                                      \
        s_ = li_ ? ends[li_ - 1] : 0;                                          \
        cn_ = ends[li_] - s_;                                                  \
    } else {                                                                   \
        _Pragma("unroll")                                                      \
        for (int j = 0; j < 16; j++) acc_[j] = 0.f;                            \
    }                                                                          \
    int mx_ = cn_;                                                             \
    _Pragma("unroll")                                                          \
    for (int m = 1; m < 16; m <<= 1) mx_ = max(mx_, __shfl_xor(mx_, m));       \
    for (int k = 0; k < mx_; k++) {                                            \
        if (k < cn_) {                                                         \
            unsigned q_ = csr[s_ + k];                                         \
            int src_ = (int)(q_ & 0xFFFFu);                                    \
            float wv_ = upk(q_);                                               \
            uint4 rv_ = *(const uint4*)(zs + src_ * 64 + ((kgrp ^ ((src_ >> 1) & 3)) << 4)); \
            _Pragma("unroll")                                                  \
            for (int j = 0; j < 4; j++) {                                      \
                acc_[j]      += wv_ * dec_raw((rv_.x >> (8 * j)) & 0x7Fu);     \
                acc_[4 + j]  += wv_ * dec_raw((rv_.y >> (8 * j)) & 0x7Fu);     \
                acc_[8 + j]  += wv_ * dec_raw((rv_.z >> (8 * j)) & 0x7Fu);     \
                acc_[12 + j] += wv_ * dec_raw((rv_.w >> (8 * j)) & 0x7Fu);     \
            }                                                                  \
        }                                                                      \
    }                                                                          \
    float scale_ = (valid_ ? dl[li_] : 0.f) * 0x1p120f;                        \
    _Pragma("unroll")                                                          \
    for (int j = 0; j < 8; j++) {                                              \
        AF0[j] = (short)f2bf(scale_ * acc_[j]);                                \
        AF1[j] = (short)f2bf(scale_ * acc_[8 + j]);                            \
    }                                                                          \
} while (0)

// W2 MFMA + epilogue for one TI (guard replaces `continue`).
#define W2_TI(TI, AF0, AF1) do {                                               \
    const int t_ = wid + (TI) * 16;                                            \
    if (t_ < 63) {                                                             \
        float4_ accv_[4];                                                      \
        _Pragma("unroll")                                                      \
        for (int c = 0; c < 4; ++c) accv_[c] = (float4_){0.f, 0.f, 0.f, 0.f};  \
        _Pragma("unroll")                                                      \
        for (int c = 0; c < 4; ++c) {                                          \
            accv_[c] = __builtin_amdgcn_mfma_f32_16x16x32_bf16(AF0, Bf[0][c], accv_[c], 0, 0, 0); \
            accv_[c] = __builtin_amdgcn_mfma_f32_16x16x32_bf16(AF1, Bf[1][c], accv_[c], 0, 0, 0); \
        }                                                                      \
        _Pragma("unroll")                                                      \
        for (int r2 = 0; r2 < 4; ++r2) {                                       \
            int li2_ = t_ * 16 + kgrp * 4 + r2;                                \
            bool valid2_ = li2_ < N_PER;                                       \
            float sp_ = 0.f;                                                   \
            _Pragma("unroll")                                                  \
            for (int c = 0; c < 4; ++c) {                                      \
                float hv_ = fmaxf(accv_[c][r2] + b2c[c], 0.f);                 \
                sp_ += hv_ * pwc[c];                                           \
                if (valid2_) zs[li2_ * 64 + c * 16 + nloc] = (unsigned char)enc_fp8(hv_); \
            }                                                                  \
            _Pragma("unroll")                                                  \
            for (int m = 1; m < 16; m <<= 1) sp_ += __shfl_xor(sp_, m);        \
            if (valid2_ && nloc == 0) {                                        \
                float scv_ = tanhf(sp_ * invn);                                \
                unsigned bits_ = __float_as_uint(scv_);                        \
                unsigned u_ = (bits_ & 0x80000000u) ? ~bits_ : (bits_ | 0x80000000u); \
                keys[li2_] = ((unsigned long long)u_ << 32) | (unsigned)(1023 - li2_); \
            }                                                                  \
        }                                                                      \
    }                                                                          \
} while (0)

// Shared front: edges->CSR->conv1->W1 (z fp8 swizzled in zs, x1b partial means).
// Emitted as a macro so both kernels share identical code.
#define FRONT_BODY() do {                                                      \
    int esrc[EPT], edst[EPT]; float eww[EPT];                                  \
    int ne = (tid < (E_PER - (EPT - 1) * 1024)) ? EPT : EPT - 1;               \
    _Pragma("unroll")                                                          \
    for (int i = 0; i < EPT; i++) {                                            \
        if (i < ne) {                                                          \
            int e = tid + i * 1024;                                            \
            esrc[i] = ei[ebase + e] - gbase;                                   \
            edst[i] = ei[ETOT + ebase + e] - gbase;                            \
            eww[i]  = ew[ebase + e];                                           \
        }                                                                      \
    }                                                                          \
    ends[tid] = 0;                                                             \
    for (int i = tid; i < N_PER * 3; i += 1024) xl[i] = x[(size_t)gbase * 3 + i]; \
    __syncthreads();                                                           \
    _Pragma("unroll")                                                          \
    for (int i = 0; i < EPT; i++)                                              \
        if (i < ne) atomicAdd(&ends[edst[i]], 1);                              \
    __syncthreads();                                                           \
    int v = ends[tid];                                                         \
    int sc = v;                                                                \
    _Pragma("unroll")                                                          \
    for (int m = 1; m < 64; m <<= 1) {                                         \
        int t = __shfl_up(sc, m);                                              \
        if (lane >= m) sc += t;                                                \
    }                                                                          \
    if (lane == 63) wpart[wid] = sc;                                           \
    __syncthreads();                                                           \
    if (tid < 16) {                                                            \
        int s2 = wpart[tid];                                                   \
        _Pragma("unroll")                                                      \
        for (int m = 1; m < 16; m <<= 1) {                                     \
            int t = __shfl_up(s2, m);                                          \
            if (tid >= m) s2 += t;                                             \
        }                                                                      \
        wpart[tid] = s2;                                                       \
    }                                                                          \
    __syncthreads();                                                           \
    int incl = sc + (wid > 0 ? wpart[wid - 1] : 0);                            \
    ends[tid] = incl;                                                          \
    posc[tid] = incl - v;                                                      \
    __syncthreads();                                                           \
    _Pragma("unroll")                                                          \
    for (int i = 0; i < EPT; i++)                                              \
        if (i < ne) {                                                          \
            int p = atomicAdd(&posc[edst[i]], 1);                              \
            csr[p] = ((unsigned)f2bf(eww[i]) << 16) | (unsigned)esrc[i];       \
        }                                                                      \
    __syncthreads();                                                           \
    float dmy = 0.f;                                                           \
    int s0i = 0, e0i = 0;                                                      \
    if (tid < N_PER) {                                                         \
        s0i = tid ? ends[tid - 1] : 0;                                         \
        e0i = ends[tid];                                                       \
        float s0 = 0.f, s1 = 0.f;                                              \
        int k = s0i;                                                           \
        for (; k + 2 <= e0i; k += 2) { s0 += upk(csr[k]); s1 += upk(csr[k + 1]); } \
        if (k < e0i) s0 += upk(csr[k]);                                        \
        dmy = rsqrtf(s0 + s1 + 1.0f);                                          \
        dl[tid] = dmy;                                                         \
        xl[tid * 3 + 0] *= dmy;                                                \
        xl[tid * 3 + 1] *= dmy;                                                \
        xl[tid * 3 + 2] *= dmy;                                                \
    }                                                                          \
    __syncthreads();                                                           \
    if (tid < N_PER) {                                                         \
        float a0 = xl[tid * 3 + 0], a1 = xl[tid * 3 + 1], a2 = xl[tid * 3 + 2];\
        for (int k = s0i; k < e0i; k++) {                                      \
            unsigned q = csr[k];                                               \
            int i0 = (int)(q & 0xFFFFu) * 3;                                   \
            float wv = upk(q);                                                 \
            a0 += wv * xl[i0]; a1 += wv * xl[i0 + 1]; a2 += wv * xl[i0 + 2];   \
        }                                                                      \
        aggv[tid * 3 + 0] = dmy * a0;                                          \
        aggv[tid * 3 + 1] = dmy * a1;                                          \
        aggv[tid * 3 + 2] = dmy * a2;                                          \
    }                                                                          \
    __syncthreads();                                                           \
    {                                                                          \
        float w0 = w1[lane], w1v = w1[64 + lane], w2v = w1[128 + lane], bf = b1[lane]; \
        float* sred = (float*)(uA + 12288);                                    \
        float px = 0.f;                                                        \
        int chunk = (lane & 31) >> 3;                                          \
        int word  = ((lane >= 32) ? 2 : 0) + ((lane & 7) >> 2);                \
        for (int node = wid; node < N_PER; node += 16) {                       \
            float a0 = aggv[node * 3], a1 = aggv[node * 3 + 1], a2 = aggv[node * 3 + 2]; \
            float hv = fmaxf(a0 * w0 + a1 * w1v + a2 * w2v + bf, 0.f);         \
            px += hv;                                                          \
            unsigned byte = enc_fp8(dl[node] * hv);                            \
            unsigned t1 = __shfl_xor(byte, 1);                                 \
            unsigned v16 = (lane & 1) ? (t1 | (byte << 8)) : (byte | (t1 << 8)); \
            unsigned t2 = __shfl_xor(v16, 2);                                  \
            unsigned v32 = (lane & 2) ? (t2 | (v16 << 16)) : (v16 | (t2 << 16)); \
            if ((lane & 3) == 0) {                                             \
                int cs = chunk ^ ((node >> 1) & 3);                            \
                *(unsigned*)(zs + node * 64 + cs * 16 + word * 4) = v32;       \
            }                                                                  \
        }                                                                      \
        sred[wid * 64 + lane] = px;                                            \
        __syncthreads();                                                       \
        if (tid < 64) {                                                        \
            float t = 0.f;                                                     \
            for (int r = 0; r < 16; r++) t += sred[r * 64 + tid];              \
            x1b[tid] = t * (1.0f / N_PER);                                     \
        }                                                                      \
    }                                                                          \
} while (0)

// W2 prologue: Bf fragments + per-column consts + pw norm.
#define W2_SETUP() do {                                                        \
    _Pragma("unroll")                                                          \
    for (int kh = 0; kh < 2; ++kh)                                             \
        _Pragma("unroll")                                                      \
        for (int c = 0; c < 4; ++c) {                                          \
            short8 t;                                                          \
            _Pragma("unroll")                                                  \
            for (int j = 0; j < 8; ++j)                                        \
                t[j] = (short)f2bf(w2[(kh * 32 + kgrp * 8 + j) * 64 + c * 16 + nloc]); \
            Bf[kh][c] = t;                                                     \
        }                                                                      \
    _Pragma("unroll")                                                          \
    for (int c = 0; c < 4; ++c) {                                              \
        b2c[c] = b2[c * 16 + nloc];                                            \
        pwc[c] = pw[c * 16 + nloc];                                            \
    }                                                                          \
    {                                                                          \
        float p = pw[lane], pn = p * p;                                        \
        _Pragma("unroll")                                                      \
        for (int m = 32; m; m >>= 1) pn += __shfl_xor(pn, m);                  \
        invn = rsqrtf(pn);                                                     \
    }                                                                          \
} while (0)

// sort + topk-mean + MLP tail (operates on keys/zs/x1b in LDS).
#define TAIL_BODY(OUTIDX) do {                                                 \
    {                                                                          \
        unsigned long long key = keys[tid];                                    \
        for (int k = 2; k <= 1024; k <<= 1) {                                  \
            for (int j = k >> 1; j > 0; j >>= 1) {                             \
                bool desc = (tid & k) == 0;                                    \
                unsigned long long p;                                          \
                if (j >= 64) {                                                 \
                    keys[tid] = key;                                           \
                    __syncthreads();                                           \
                    p = keys[tid ^ j];                                         \
                    __syncthreads();                                           \
                } else {                                                       \
                    p = __shfl_xor(key, j);                                    \
                }                                                              \
                bool low = (tid & j) == 0;                                     \
                bool sw = low ? (desc ? (key < p) : (key > p))                 \
                              : (desc ? (p < key) : (p > key));                \
                if (sw) key = p;                                               \
            }                                                                  \
        }                                                                      \
        keys[tid] = key;                                                       \
    }                                                                          \
    __syncthreads();                                                           \
    float* red   = (float*)(uA + 8192);                                        \
    float* a1buf = (float*)(uA + 12288);                                       \
    float* a2buf = (float*)(uA + 12544);                                       \
    float* zbuf  = (float*)(uA + 12672);                                       \
    {                                                                          \
        int f = tid & 63, w16 = tid >> 6;                                      \
        float acc2 = 0.f;                                                      \
        for (int r = w16; r < KSEL; r += 16) {                                 \
            unsigned long long key = keys[r];                                  \
            int idx = 1023 - (int)(key & 0xFFFFFFFFu);                         \
            unsigned u = (unsigned)(key >> 32);                                \
            unsigned bits = (u & 0x80000000u) ? (u & 0x7FFFFFFFu) : ~u;        \
            float valS = __uint_as_float(bits) * 0x1p120f;                     \
            acc2 += valS * dec_raw((unsigned)zs[idx * 64 + f] & 0x7Fu);        \
        }                                                                      \
        red[tid] = acc2;                                                       \
    }                                                                          \
    __syncthreads();                                                           \
    if (tid < 64) {                                                            \
        float s2 = 0.f;                                                        \
        for (int ww = 0; ww < 16; ww++) s2 += red[ww * 64 + tid];              \
        zbuf[tid] = x1b[tid] + s2 * (1.0f / KSEL);                             \
    }                                                                          \
    __syncthreads();                                                           \
    if (tid < 64) {                                                            \
        float a = l1b[tid];                                                    \
        for (int k = 0; k < 64; k++) a += zbuf[k] * l1w[k * 64 + tid];         \
        a1buf[tid] = fmaxf(a, 0.f);                                            \
    }                                                                          \
    __syncthreads();                                                           \
    if (tid < 32) {                                                            \
        float a = l2b[tid];                                                    \
        for (int k = 0; k < 64; k++) a += a1buf[k] * l2w[k * 32 + tid];        \
        a2buf[tid] = fmaxf(a, 0.f);                                            \
    }                                                                          \
    __syncthreads();                                                           \
    if (tid == 0) {                                                            \
        float t = l3b[0];                                                      \
        for (int k = 0; k < 32; k++) t += a2buf[k] * l3w[k];                   \
        out[OUTIDX] = 1.0f / (1.0f + expf(-t));                                \
    }                                                                          \
} while (0)

#define SMEM_DECLS()                                                           \
    __shared__ __align__(16) unsigned char smem[136832];                       \
    unsigned char* zs = smem;                                                  \
    float* xl = (float*)smem;                                                  \
    unsigned* csr = (unsigned*)(smem + 64000);                                 \
    int*   ends = (int*)(smem + 112000);                                       \
    float* dl   = (float*)(smem + 116096);                                     \
    int*   posc = (int*)(smem + 116096);                                       \
    int*   wpart = (int*)(smem + 120192);                                      \
    float* x1b   = (float*)(smem + 120192);                                    \
    unsigned char* uA = smem + 120448;                                         \
    float* aggv = (float*)uA;

#define PARAMS                                                                 \
    const int* __restrict__ ei, const float* __restrict__ ew,                  \
    const float* __restrict__ x,                                               \
    const float* __restrict__ w1, const float* __restrict__ b1,                \
    const float* __restrict__ w2, const float* __restrict__ b2,                \
    const float* __restrict__ pw,                                              \
    const float* __restrict__ l1w, const float* __restrict__ l1b,              \
    const float* __restrict__ l2w, const float* __restrict__ l2b,              \
    const float* __restrict__ l3w, const float* __restrict__ l3b,              \
    float* __restrict__ out

// ===== single-block-per-graph kernel (r4-proven fallback path) =====
__global__ __launch_bounds__(1024)
__attribute__((amdgpu_waves_per_eu(4, 4))) void k_all_single(PARAMS) {
    SMEM_DECLS();
    int g = blockIdx.x, tid = threadIdx.x;
    int wid = tid >> 6, lane = tid & 63;
    int gbase = g * N_PER, ebase = g * E_PER;
    FRONT_BODY();
    int kgrp = lane >> 4, nloc = lane & 15;
    short8 Af0a, Af0b, Af1a, Af1b, Af2a, Af2b, Af3a, Af3b;
    CONV2_TI(0, Af0a, Af0b);
    CONV2_TI(1, Af1a, Af1b);
    CONV2_TI(2, Af2a, Af2b);
    CONV2_TI(3, Af3a, Af3b);
    __syncthreads();
    unsigned long long* keys = (unsigned long long*)uA;
    {
        short8 Bf[2][4]; float b2c[4], pwc[4], invn;
        W2_SETUP();
        if (tid >= N_PER) keys[tid] = 0ull;
        W2_TI(0, Af0a, Af0b);
        W2_TI(1, Af1a, Af1b);
        W2_TI(2, Af2a, Af2b);
        W2_TI(3, Af3a, Af3b);
    }
    __syncthreads();
    TAIL_BODY(g);
}

// ===== pair-split kernel: 2 blocks per graph (r6/r7) =====
// Both halves duplicate the front (full z in own LDS). conv2+W2 split by node
// half: P0 = TI{0,1}, P1 = TI{2,3}. P1 publishes h2 rows 512..999 + keys
// [512,1024) to ws, release-signals; P0 bounded-acquire-spins, copies in,
// runs sort+topk+MLP. Spin bound ~0.2s: if co-residency fails we produce a
// wrong answer (diagnostic) instead of a hung container.
// ws: [0,512) flags u32[100]; [4096+g*32768) h2; [4096+100*32768+g*4096) keys.
__global__ __launch_bounds__(1024)
__attribute__((amdgpu_waves_per_eu(4, 4))) void k_all_pair(
    PARAMS, unsigned char* __restrict__ ws) {
    SMEM_DECLS();
    int g = blockIdx.x >> 1, half = blockIdx.x & 1, tid = threadIdx.x;
    int wid = tid >> 6, lane = tid & 63;
    int gbase = g * N_PER, ebase = g * E_PER;
    unsigned int* flag = (unsigned int*)ws;
    unsigned char* h2x = ws + 4096 + (size_t)g * 32768;
    unsigned long long* kx =
        (unsigned long long*)(ws + 4096 + 100 * 32768 + (size_t)g * 4096);

    FRONT_BODY();
    int kgrp = lane >> 4, nloc = lane & 15;
    const int tiA = half * 2, tiB = half * 2 + 1;
    short8 AfAa, AfAb, AfBa, AfBb;
    CONV2_TI(tiA, AfAa, AfAb);
    CONV2_TI(tiB, AfBa, AfBb);
    __syncthreads();   // all z reads done; zs may be overwritten with h2
    unsigned long long* keys = (unsigned long long*)uA;
    {
        short8 Bf[2][4]; float b2c[4], pwc[4], invn;
        W2_SETUP();
        if (tid >= N_PER) keys[tid] = 0ull;
        W2_TI(tiA, AfAa, AfAb);
        W2_TI(tiB, AfBa, AfBb);
    }
    __syncthreads();                             // h2 + keys (own half) done
    if (half) {
        const uint4* srcv = (const uint4*)(zs + 32768);   // h2 rows 512..999
        uint4* dstv = (uint4*)h2x;
        for (int i = tid; i < 1952; i += 1024) dstv[i] = srcv[i];
        for (int i = tid; i < 512; i += 1024) kx[i] = keys[512 + i];
        __syncthreads();                         // all publish stores done
        if (tid == 0)
            __hip_atomic_store(flag + g, 1u, __ATOMIC_RELEASE,
                               __HIP_MEMORY_SCOPE_AGENT);
        return;
    }
    if (tid == 0) {
        for (int it = 0; it < 1000000; ++it) {   // ~0.2s cap >> 100us legit wait
            if (__hip_atomic_load(flag + g, __ATOMIC_ACQUIRE,
                                  __HIP_MEMORY_SCOPE_AGENT) != 0u) break;
            __builtin_amdgcn_s_sleep(8);
        }
    }
    __syncthreads();
    {
        uint4* dstv = (uint4*)(zs + 32768);
        const uint4* srcv = (const uint4*)h2x;
        for (int i = tid; i < 1952; i += 1024) dstv[i] = srcv[i];
        for (int i = tid; i < 512; i += 1024) keys[512 + i] = kx[i];
    }
    __syncthreads();
    TAIL_BODY(g);
}

extern "C" void kernel_launch(void* const* d_in, const int* in_sizes, int n_in,
                              void* d_out, int out_size, void* d_ws, size_t ws_size,
                              hipStream_t stream) {
    const float* x   = (const float*)d_in[0];
    const int*   ei  = (const int*)d_in[1];
    const float* ew  = (const float*)d_in[2];
    const float* c1w = (const float*)d_in[4];
    const float* c1b = (const float*)d_in[5];
    const float* c2w = (const float*)d_in[6];
    const float* c2b = (const float*)d_in[7];
    const float* pw  = (const float*)d_in[8];
    const float* l1w = (const float*)d_in[9];
    const float* l1b = (const float*)d_in[10];
    const float* l2w = (const float*)d_in[11];
    const float* l2b = (const float*)d_in[12];
    const float* l3w = (const float*)d_in[13];
    const float* l3b = (const float*)d_in[14];
    float* out = (float*)d_out;
    (void)in_sizes; (void)n_in; (void)out_size;

    const size_t needed = 4096 + (size_t)100 * 32768 + (size_t)100 * 4096;
    if (d_ws != nullptr && ws_size >= needed) {
        // zero pair-sync flags (async on stream: graph-capture safe)
        hipMemsetAsync(d_ws, 0, 512, stream);
        k_all_pair<<<2 * B_G, 1024, 0, stream>>>(
            ei, ew, x, c1w, c1b, c2w, c2b, pw,
            l1w, l1b, l2w, l2b, l3w, l3b, out, (unsigned char*)d_ws);
    } else {
        k_all_single<<<B_G, 1024, 0, stream>>>(
            ei, ew, x, c1w, c1b, c2w, c2b, pw,
            l1w, l1b, l2w, l2b, l3w, l3b, out);
    }
}

// Round 8
// 170.732 us; speedup vs baseline: 1.0960x; 1.0035x over previous
//
#include <hip/hip_runtime.h>

#define B_G   100
#define N_PER 1000
#define E_PER 12000
#define NTOT  (B_G * N_PER)
#define ETOT  (B_G * E_PER)
#define KSEL  800
#define EPT   12

// ---- workspace layout (bytes) ----
#define CSRB  0u                       // u32[12000] per graph, stride 49152
#define ENDB  4915200u                 // int[1024] per graph, stride 4096
#define H2B   5324800u                 // fp8 h2 [1000][64] per graph, stride 65536
#define KEYB  11878400u                // u64[1024] per graph, stride 8192
#define X1BB  12697600u                // f32[64] per graph, stride 256
#define WSNEED 12723200u

typedef __attribute__((ext_vector_type(8))) short short8;
typedef __attribute__((ext_vector_type(4))) float float4_;

__device__ __forceinline__ unsigned short f2bf(float f) {
    unsigned u = __float_as_uint(f);
    u += 0x7fffu + ((u >> 16) & 1u);          // RNE
    return (unsigned short)(u >> 16);
}
__device__ __forceinline__ float upk(unsigned q) {          // bf16 ew in hi16
    return __uint_as_float(q & 0xFFFF0000u);
}
// fp8 e4m3 (z>=0): raw decode = true_value * 2^-120 (exact, incl subnormals)
__device__ __forceinline__ float dec_raw(unsigned byte7f) { // pass (b&0x7f)
    return __uint_as_float(byte7f << 20);
}
__device__ __forceinline__ unsigned enc_fp8(float z) {      // z >= 0, z < 448
    unsigned u = __float_as_uint(z * 0x1p-120f);
    u += 0x7FFFFu + ((u >> 20) & 1u);                       // RNE at bit 20
    return u >> 20;
}

// ---- CSR build: edge load, count, scan, fill. Ends with a barrier. ----
// PRE: statement(s) run before the first barrier (xl preload in fused kernel).
#define BUILD_BODY(PRE) do {                                                   \
    int esrc[EPT], edst[EPT]; float eww[EPT];                                  \
    int ne = (tid < (E_PER - (EPT - 1) * 1024)) ? EPT : EPT - 1;               \
    _Pragma("unroll")                                                          \
    for (int i = 0; i < EPT; i++) {                                            \
        if (i < ne) {                                                          \
            int e = tid + i * 1024;                                            \
            esrc[i] = ei[ebase + e] - gbase;                                   \
            edst[i] = ei[ETOT + ebase + e] - gbase;                            \
            eww[i]  = ew[ebase + e];                                           \
        }                                                                      \
    }                                                                          \
    ends[tid] = 0;                                                             \
    PRE                                                                        \
    __syncthreads();                                                           \
    _Pragma("unroll")                                                          \
    for (int i = 0; i < EPT; i++)                                              \
        if (i < ne) atomicAdd(&ends[edst[i]], 1);                              \
    __syncthreads();                                                           \
    int v = ends[tid];                                                         \
    int sc = v;                                                                \
    _Pragma("unroll")                                                          \
    for (int m = 1; m < 64; m <<= 1) {                                         \
        int t = __shfl_up(sc, m);                                              \
        if (lane >= m) sc += t;                                                \
    }                                                                          \
    if (lane == 63) wpart[wid] = sc;                                           \
    __syncthreads();                                                           \
    if (tid < 16) {                                                            \
        int s2 = wpart[tid];                                                   \
        _Pragma("unroll")                                                      \
        for (int m = 1; m < 16; m <<= 1) {                                     \
            int t = __shfl_up(s2, m);                                          \
            if (tid >= m) s2 += t;                                             \
        }                                                                      \
        wpart[tid] = s2;                                                       \
    }                                                                          \
    __syncthreads();                                                           \
    int incl = sc + (wid > 0 ? wpart[wid - 1] : 0);                            \
    ends[tid] = incl;                                                          \
    posc[tid] = incl - v;                                                      \
    __syncthreads();                                                           \
    _Pragma("unroll")                                                          \
    for (int i = 0; i < EPT; i++)                                              \
        if (i < ne) {                                                          \
            int p = atomicAdd(&posc[edst[i]], 1);                              \
            csr[p] = ((unsigned)f2bf(eww[i]) << 16) | (unsigned)esrc[i];       \
        }                                                                      \
    __syncthreads();                                                           \
} while (0)

// ---- wsum -> dl; y=dinv*x; conv1 gather; W1 -> z fp8 swizzled + x1b ----
#define REST_BODY() do {                                                       \
    float dmy = 0.f;                                                           \
    int s0i = 0, e0i = 0;                                                      \
    if (tid < N_PER) {                                                         \
        s0i = tid ? ends[tid - 1] : 0;                                         \
        e0i = ends[tid];                                                       \
        float s0 = 0.f, s1 = 0.f;                                              \
        int k = s0i;                                                           \
        for (; k + 2 <= e0i; k += 2) { s0 += upk(csr[k]); s1 += upk(csr[k + 1]); } \
        if (k < e0i) s0 += upk(csr[k]);                                        \
        dmy = rsqrtf(s0 + s1 + 1.0f);                                          \
        dl[tid] = dmy;                                                         \
        xl[tid * 3 + 0] *= dmy;                                                \
        xl[tid * 3 + 1] *= dmy;                                                \
        xl[tid * 3 + 2] *= dmy;                                                \
    }                                                                          \
    __syncthreads();                                                           \
    if (tid < N_PER) {                                                         \
        float a0 = xl[tid * 3 + 0], a1 = xl[tid * 3 + 1], a2 = xl[tid * 3 + 2];\
        for (int k = s0i; k < e0i; k++) {                                      \
            unsigned q = csr[k];                                               \
            int i0 = (int)(q & 0xFFFFu) * 3;                                   \
            float wv = upk(q);                                                 \
            a0 += wv * xl[i0]; a1 += wv * xl[i0 + 1]; a2 += wv * xl[i0 + 2];   \
        }                                                                      \
        aggv[tid * 3 + 0] = dmy * a0;                                          \
        aggv[tid * 3 + 1] = dmy * a1;                                          \
        aggv[tid * 3 + 2] = dmy * a2;                                          \
    }                                                                          \
    __syncthreads();                                                           \
    {                                                                          \
        float w0 = w1[lane], w1v = w1[64 + lane], w2v = w1[128 + lane], bf = b1[lane]; \
        float* sred = (float*)(uA + 12288);                                    \
        float px = 0.f;                                                        \
        int chunk = (lane & 31) >> 3;                                          \
        int word  = ((lane >= 32) ? 2 : 0) + ((lane & 7) >> 2);                \
        for (int node = wid; node < N_PER; node += 16) {                       \
            float a0 = aggv[node * 3], a1 = aggv[node * 3 + 1], a2 = aggv[node * 3 + 2]; \
            float hv = fmaxf(a0 * w0 + a1 * w1v + a2 * w2v + bf, 0.f);         \
            px += hv;                                                          \
            unsigned byte = enc_fp8(dl[node] * hv);                            \
            unsigned t1 = __shfl_xor(byte, 1);                                 \
            unsigned v16 = (lane & 1) ? (t1 | (byte << 8)) : (byte | (t1 << 8)); \
            unsigned t2 = __shfl_xor(v16, 2);                                  \
            unsigned v32 = (lane & 2) ? (t2 | (v16 << 16)) : (v16 | (t2 << 16)); \
            if ((lane & 3) == 0) {                                             \
                int cs = chunk ^ ((node >> 1) & 3);                            \
                *(unsigned*)(zs + node * 64 + cs * 16 + word * 4) = v32;       \
            }                                                                  \
        }                                                                      \
        sred[wid * 64 + lane] = px;                                            \
        __syncthreads();                                                       \
        if (tid < 64) {                                                        \
            float t = 0.f;                                                     \
            for (int r = 0; r < 16; r++) t += sred[r * 64 + tid];              \
            x1b[tid] = t * (1.0f / N_PER);                                     \
        }                                                                      \
    }                                                                          \
} while (0)

// conv2 aggregation for one TI (runtime TI ok: used arithmetically only);
// results into named short8 AF0/AF1 (r3: named vars keep fragments off stack).
#define CONV2_TI(TI, AF0, AF1) do {                                            \
    const int t_ = wid + (TI) * 16;                                            \
    const int li_ = t_ * 16 + nloc;                                            \
    const bool valid_ = li_ < N_PER;                                           \
    float acc_[16];                                                            \
    int s_ = 0, cn_ = 0;                                                       \
    if (valid_) {                                                              \
        uint4 rv_ = *(const uint4*)(zs + li_ * 64 + ((kgrp ^ ((li_ >> 1) & 3)) << 4)); \
        _Pragma("unroll")                                                      \
        for (int j = 0; j < 4; j++) {                                          \
            acc_[j]      = dec_raw((rv_.x >> (8 * j)) & 0x7Fu);                \
            acc_[4 + j]  = dec_raw((rv_.y >> (8 * j)) & 0x7Fu);                \
            acc_[8 + j]  = dec_raw((rv_.z >> (8 * j)) & 0x7Fu);                \
            acc_[12 + j] = dec_raw((rv_.w >> (8 * j)) & 0x7Fu);                \
        }                                                                      \
        s_ = li_ ? ends[li_ - 1] : 0;                                          \
        cn_ = ends[li_] - s_;                                                  \
    } else {                                                                   \
        _Pragma("unroll")                                                      \
        for (int j = 0; j < 16; j++) acc_[j] = 0.f;                            \
    }                                                                          \
    int mx_ = cn_;                                                             \
    _Pragma("unroll")                                                          \
    for (int m = 1; m < 16; m <<= 1) mx_ = max(mx_, __shfl_xor(mx_, m));       \
    for (int k = 0; k < mx_; k++) {                                            \
        if (k < cn_) {                                                         \
            unsigned q_ = csr[s_ + k];                                         \
            int src_ = (int)(q_ & 0xFFFFu);                                    \
            float wv_ = upk(q_);                                               \
            uint4 rv_ = *(const uint4*)(zs + src_ * 64 + ((kgrp ^ ((src_ >> 1) & 3)) << 4)); \
            _Pragma("unroll")                                                  \
            for (int j = 0; j < 4; j++) {                                      \
                acc_[j]      += wv_ * dec_raw((rv_.x >> (8 * j)) & 0x7Fu);     \
                acc_[4 + j]  += wv_ * dec_raw((rv_.y >> (8 * j)) & 0x7Fu);     \
                acc_[8 + j]  += wv_ * dec_raw((rv_.z >> (8 * j)) & 0x7Fu);     \
                acc_[12 + j] += wv_ * dec_raw((rv_.w >> (8 * j)) & 0x7Fu);     \
            }                                                                  \
        }                                                                      \
    }                                                                          \
    float scale_ = (valid_ ? dl[li_] : 0.f) * 0x1p120f;                        \
    _Pragma("unroll")                                                          \
    for (int j = 0; j < 8; j++) {                                              \
        AF0[j] = (short)f2bf(scale_ * acc_[j]);                                \
        AF1[j] = (short)f2bf(scale_ * acc_[8 + j]);                            \
    }                                                                          \
} while (0)

// W2 MFMA + epilogue for one TI (guard replaces `continue`).
#define W2_TI(TI, AF0, AF1) do {                                               \
    const int t_ = wid + (TI) * 16;                                            \
    if (t_ < 63) {                                                             \
        float4_ accv_[4];                                                      \
        _Pragma("unroll")                                                      \
        for (int c = 0; c < 4; ++c) accv_[c] = (float4_){0.f, 0.f, 0.f, 0.f};  \
        _Pragma("unroll")                                                      \
        for (int c = 0; c < 4; ++c) {                                          \
            accv_[c] = __builtin_amdgcn_mfma_f32_16x16x32_bf16(AF0, Bf[0][c], accv_[c], 0, 0, 0); \
            accv_[c] = __builtin_amdgcn_mfma_f32_16x16x32_bf16(AF1, Bf[1][c], accv_[c], 0, 0, 0); \
        }                                                                      \
        _Pragma("unroll")                                                      \
        for (int r2 = 0; r2 < 4; ++r2) {                                       \
            int li2_ = t_ * 16 + kgrp * 4 + r2;                                \
            bool valid2_ = li2_ < N_PER;                                       \
            float sp_ = 0.f;                                                   \
            _Pragma("unroll")                                                  \
            for (int c = 0; c < 4; ++c) {                                      \
                float hv_ = fmaxf(accv_[c][r2] + b2c[c], 0.f);                 \
                sp_ += hv_ * pwc[c];                                           \
                if (valid2_) zs[li2_ * 64 + c * 16 + nloc] = (unsigned char)enc_fp8(hv_); \
            }                                                                  \
            _Pragma("unroll")                                                  \
            for (int m = 1; m < 16; m <<= 1) sp_ += __shfl_xor(sp_, m);        \
            if (valid2_ && nloc == 0) {                                        \
                float scv_ = tanhf(sp_ * invn);                                \
                unsigned bits_ = __float_as_uint(scv_);                        \
                unsigned u_ = (bits_ & 0x80000000u) ? ~bits_ : (bits_ | 0x80000000u); \
                keys[li2_] = ((unsigned long long)u_ << 32) | (unsigned)(1023 - li2_); \
            }                                                                  \
        }                                                                      \
    }                                                                          \
} while (0)

// W2 prologue: Bf fragments + per-column consts + pw norm.
#define W2_SETUP() do {                                                        \
    _Pragma("unroll")                                                          \
    for (int kh = 0; kh < 2; ++kh)                                             \
        _Pragma("unroll")                                                      \
        for (int c = 0; c < 4; ++c) {                                          \
            short8 t;                                                          \
            _Pragma("unroll")                                                  \
            for (int j = 0; j < 8; ++j)                                        \
                t[j] = (short)f2bf(w2[(kh * 32 + kgrp * 8 + j) * 64 + c * 16 + nloc]); \
            Bf[kh][c] = t;                                                     \
        }                                                                      \
    _Pragma("unroll")                                                          \
    for (int c = 0; c < 4; ++c) {                                              \
        b2c[c] = b2[c * 16 + nloc];                                            \
        pwc[c] = pw[c * 16 + nloc];                                            \
    }                                                                          \
    {                                                                          \
        float p = pw[lane], pn = p * p;                                        \
        _Pragma("unroll")                                                      \
        for (int m = 32; m; m >>= 1) pn += __shfl_xor(pn, m);                  \
        invn = rsqrtf(pn);                                                     \
    }                                                                          \
} while (0)

// sort + topk-mean + MLP tail. Requires locals: keys, zs(h2), red, a1buf,
// a2buf, zbuf, x1b, tid, and the l* weights.
#define TAIL_BODY(OUTIDX) do {                                                 \
    {                                                                          \
        unsigned long long key = keys[tid];                                    \
        for (int k = 2; k <= 1024; k <<= 1) {                                  \
            for (int j = k >> 1; j > 0; j >>= 1) {                             \
                bool desc = (tid & k) == 0;                                    \
                unsigned long long p;                                          \
                if (j >= 64) {                                                 \
                    keys[tid] = key;                                           \
                    __syncthreads();                                           \
                    p = keys[tid ^ j];                                         \
                    __syncthreads();                                           \
                } else {                                                       \
                    p = __shfl_xor(key, j);                                    \
                }                                                              \
                bool low = (tid & j) == 0;                                     \
                bool sw = low ? (desc ? (key < p) : (key > p))                 \
                              : (desc ? (p < key) : (p > key));                \
                if (sw) key = p;                                               \
            }                                                                  \
        }                                                                      \
        keys[tid] = key;                                                       \
    }                                                                          \
    __syncthreads();                                                           \
    {                                                                          \
        int f = tid & 63, w16 = tid >> 6;                                      \
        float acc2 = 0.f;                                                      \
        for (int r = w16; r < KSEL; r += 16) {                                 \
            unsigned long long key = keys[r];                                  \
            int idx = 1023 - (int)(key & 0xFFFFFFFFu);                         \
            unsigned u = (unsigned)(key >> 32);                                \
            unsigned bits = (u & 0x80000000u) ? (u & 0x7FFFFFFFu) : ~u;        \
            float valS = __uint_as_float(bits) * 0x1p120f;                     \
            acc2 += valS * dec_raw((unsigned)zs[idx * 64 + f] & 0x7Fu);        \
        }                                                                      \
        red[tid] = acc2;                                                       \
    }                                                                          \
    __syncthreads();                                                           \
    if (tid < 64) {                                                            \
        float s2 = 0.f;                                                        \
        for (int ww = 0; ww < 16; ww++) s2 += red[ww * 64 + tid];              \
        zbuf[tid] = x1b[tid] + s2 * (1.0f / KSEL);                             \
    }                                                                          \
    __syncthreads();                                                           \
    if (tid < 64) {                                                            \
        float a = l1b[tid];                                                    \
        for (int k = 0; k < 64; k++) a += zbuf[k] * l1w[k * 64 + tid];         \
        a1buf[tid] = fmaxf(a, 0.f);                                            \
    }                                                                          \
    __syncthreads();                                                           \
    if (tid < 32) {                                                            \
        float a = l2b[tid];                                                    \
        for (int k = 0; k < 64; k++) a += a1buf[k] * l2w[k * 32 + tid];        \
        a2buf[tid] = fmaxf(a, 0.f);                                            \
    }                                                                          \
    __syncthreads();                                                           \
    if (tid == 0) {                                                            \
        float t = l3b[0];                                                      \
        for (int k = 0; k < 32; k++) t += a2buf[k] * l3w[k];                   \
        out[OUTIDX] = 1.0f / (1.0f + expf(-t));                                \
    }                                                                          \
} while (0)

#define SMEM_DECLS()                                                           \
    __shared__ __align__(16) unsigned char smem[136832];                       \
    unsigned char* zs = smem;                                                  \
    float* xl = (float*)smem;                                                  \
    unsigned* csr = (unsigned*)(smem + 64000);                                 \
    int*   ends = (int*)(smem + 112000);                                       \
    float* dl   = (float*)(smem + 116096);                                     \
    int*   posc = (int*)(smem + 116096);                                       \
    int*   wpart = (int*)(smem + 120192);                                      \
    float* x1b   = (float*)(smem + 120192);                                    \
    unsigned char* uA = smem + 120448;                                         \
    float* aggv = (float*)uA;                                                  \
    (void)posc; (void)wpart; (void)aggv;

// ===== k_build: CSR construction, 1 block/graph; persists csr+ends to ws ====
__global__ __launch_bounds__(1024) void k_build(
    const int* __restrict__ ei, const float* __restrict__ ew,
    unsigned char* __restrict__ ws) {
    __shared__ __align__(16) unsigned csr[12000];
    __shared__ int ends[1024];
    __shared__ int posc[1024];
    __shared__ int wpart[16];
    int g = blockIdx.x, tid = threadIdx.x;
    int wid = tid >> 6, lane = tid & 63;
    int gbase = g * N_PER, ebase = g * E_PER;
    BUILD_BODY();
    // dump csr (3000 uint4) + ends
    {
        uint4* cw = (uint4*)(ws + CSRB + (size_t)g * 49152);
        const uint4* cs = (const uint4*)csr;
        for (int i = tid; i < 3000; i += 1024) cw[i] = cs[i];
        ((int*)(ws + ENDB + (size_t)g * 4096))[tid] = ends[tid];
    }
}

// ===== k_mid: 2 blocks/graph; wsum+conv1+W1 (dup), conv2+W2 own half;
// publishes h2-half + keys-half (+x1b from half0) to ws ====
__global__ __launch_bounds__(1024)
__attribute__((amdgpu_waves_per_eu(4, 4))) void k_mid(
    const float* __restrict__ x,
    const float* __restrict__ w1, const float* __restrict__ b1,
    const float* __restrict__ w2, const float* __restrict__ b2,
    const float* __restrict__ pw, unsigned char* __restrict__ ws) {
    SMEM_DECLS();
    int g = blockIdx.x >> 1, half = blockIdx.x & 1, tid = threadIdx.x;
    int wid = tid >> 6, lane = tid & 63;
    int gbase = g * N_PER;
    // load csr + ends from ws; xl from x
    {
        const uint4* cs = (const uint4*)(ws + CSRB + (size_t)g * 49152);
        uint4* cd = (uint4*)csr;
        for (int i = tid; i < 3000; i += 1024) cd[i] = cs[i];
        ends[tid] = ((const int*)(ws + ENDB + (size_t)g * 4096))[tid];
        for (int i = tid; i < N_PER * 3; i += 1024) xl[i] = x[(size_t)gbase * 3 + i];
    }
    __syncthreads();
    REST_BODY();
    // conv2 + W2 for own half
    int kgrp = lane >> 4, nloc = lane & 15;
    const int tiA = half * 2, tiB = half * 2 + 1;
    short8 AfAa, AfAb, AfBa, AfBb;
    CONV2_TI(tiA, AfAa, AfAb);
    CONV2_TI(tiB, AfBa, AfBb);
    __syncthreads();   // all z reads done; zs may be overwritten with h2
    unsigned long long* keys = (unsigned long long*)uA;
    {
        short8 Bf[2][4]; float b2c[4], pwc[4], invn;
        W2_SETUP();
        if (tid >= N_PER) keys[tid] = 0ull;      // pad entries (half1 range)
        W2_TI(tiA, AfAa, AfAb);
        W2_TI(tiB, AfBa, AfBb);
    }
    __syncthreads();                             // h2 + keys (own half) done
    // publish own half
    {
        uint4* d = (uint4*)(ws + H2B + (size_t)g * 65536 + (size_t)half * 32768);
        const uint4* s = (const uint4*)(zs + half * 32768);
        int n = half ? 1952 : 2048;              // rows 512..999 vs 0..511
        for (int i = tid; i < n; i += 1024) d[i] = s[i];
        unsigned long long* kw =
            (unsigned long long*)(ws + KEYB + (size_t)g * 8192);
        for (int i = tid; i < 512; i += 1024)
            kw[half * 512 + i] = keys[half * 512 + i];
        if (!half && tid < 64)
            ((float*)(ws + X1BB + (size_t)g * 256))[tid] = x1b[tid];
    }
}

// ===== k_tail: 1 block/graph; sort + topk-mean + MLP ====
__global__ __launch_bounds__(1024) void k_tail(
    const float* __restrict__ l1w, const float* __restrict__ l1b,
    const float* __restrict__ l2w, const float* __restrict__ l2b,
    const float* __restrict__ l3w, const float* __restrict__ l3b,
    float* __restrict__ out, const unsigned char* __restrict__ ws) {
    __shared__ __align__(16) unsigned char sm2[77184];
    unsigned char* zs = sm2;                                   // h2 [1000][64]
    unsigned long long* keys = (unsigned long long*)(sm2 + 64000);
    float* red   = (float*)(sm2 + 72192);
    float* x1b   = (float*)(sm2 + 76288);
    float* a1buf = (float*)(sm2 + 76544);
    float* a2buf = (float*)(sm2 + 76800);
    float* zbuf  = (float*)(sm2 + 76928);
    int g = blockIdx.x, tid = threadIdx.x;
    {
        uint4* hd = (uint4*)zs;
        const uint4* hs = (const uint4*)(ws + H2B + (size_t)g * 65536);
        for (int i = tid; i < 4000; i += 1024) hd[i] = hs[i];
        keys[tid] = ((const unsigned long long*)(ws + KEYB + (size_t)g * 8192))[tid];
        if (tid < 64) x1b[tid] = ((const float*)(ws + X1BB + (size_t)g * 256))[tid];
    }
    __syncthreads();
    TAIL_BODY(g);
}

// ===== fallback: r4-proven single kernel (used if ws too small) ====
__global__ __launch_bounds__(1024)
__attribute__((amdgpu_waves_per_eu(4, 4))) void k_all_single(
    const int* __restrict__ ei, const float* __restrict__ ew,
    const float* __restrict__ x,
    const float* __restrict__ w1, const float* __restrict__ b1,
    const float* __restrict__ w2, const float* __restrict__ b2,
    const float* __restrict__ pw,
    const float* __restrict__ l1w, const float* __restrict__ l1b,
    const float* __restrict__ l2w, const float* __restrict__ l2b,
    const float* __restrict__ l3w, const float* __restrict__ l3b,
    float* __restrict__ out) {
    SMEM_DECLS();
    int g = blockIdx.x, tid = threadIdx.x;
    int wid = tid >> 6, lane = tid & 63;
    int gbase = g * N_PER, ebase = g * E_PER;
    BUILD_BODY(for (int i = tid; i < N_PER * 3; i += 1024) xl[i] = x[(size_t)gbase * 3 + i];);
    REST_BODY();
    int kgrp = lane >> 4, nloc = lane & 15;
    short8 Af0a, Af0b, Af1a, Af1b, Af2a, Af2b, Af3a, Af3b;
    CONV2_TI(0, Af0a, Af0b);
    CONV2_TI(1, Af1a, Af1b);
    CONV2_TI(2, Af2a, Af2b);
    CONV2_TI(3, Af3a, Af3b);
    __syncthreads();
    unsigned long long* keys = (unsigned long long*)uA;
    {
        short8 Bf[2][4]; float b2c[4], pwc[4], invn;
        W2_SETUP();
        if (tid >= N_PER) keys[tid] = 0ull;
        W2_TI(0, Af0a, Af0b);
        W2_TI(1, Af1a, Af1b);
        W2_TI(2, Af2a, Af2b);
        W2_TI(3, Af3a, Af3b);
    }
    __syncthreads();
    float* red   = (float*)(uA + 8192);
    float* a1buf = (float*)(uA + 12288);
    float* a2buf = (float*)(uA + 12544);
    float* zbuf  = (float*)(uA + 12672);
    TAIL_BODY(g);
}

extern "C" void kernel_launch(void* const* d_in, const int* in_sizes, int n_in,
                              void* d_out, int out_size, void* d_ws, size_t ws_size,
                              hipStream_t stream) {
    const float* x   = (const float*)d_in[0];
    const int*   ei  = (const int*)d_in[1];
    const float* ew  = (const float*)d_in[2];
    const float* c1w = (const float*)d_in[4];
    const float* c1b = (const float*)d_in[5];
    const float* c2w = (const float*)d_in[6];
    const float* c2b = (const float*)d_in[7];
    const float* pw  = (const float*)d_in[8];
    const float* l1w = (const float*)d_in[9];
    const float* l1b = (const float*)d_in[10];
    const float* l2w = (const float*)d_in[11];
    const float* l2b = (const float*)d_in[12];
    const float* l3w = (const float*)d_in[13];
    const float* l3b = (const float*)d_in[14];
    float* out = (float*)d_out;
    (void)in_sizes; (void)n_in; (void)out_size;

    if (d_ws != nullptr && ws_size >= (size_t)WSNEED) {
        unsigned char* ws = (unsigned char*)d_ws;
        k_build<<<B_G, 1024, 0, stream>>>(ei, ew, ws);
        k_mid<<<2 * B_G, 1024, 0, stream>>>(x, c1w, c1b, c2w, c2b, pw, ws);
        k_tail<<<B_G, 1024, 0, stream>>>(l1w, l1b, l2w, l2b, l3w, l3b, out, ws);
    } else {
        k_all_single<<<B_G, 1024, 0, stream>>>(
            ei, ew, x, c1w, c1b, c2w, c2b, pw,
            l1w, l1b, l2w, l2b, l3w, l3b, out);
    }
}